// Round 6
// baseline (94.562 us; speedup 1.0000x reference)
//
#include <hip/hip_runtime.h>
#include <math.h>

#define DIM 2048
#define NB 32
#define NK 256
#define NJ 4   // j-chunk count = number of partial Bsum buffers

typedef float vf4 __attribute__((ext_vector_type(4)));

// ---------------- Kernel A: partial Bsum over one j-chunk ----------------
// grid (2, NJ, 32): x = i-chunk (1024 i), y = j-chunk (512 j), z = batch.
// 256 threads, 4 consecutive i per thread. j-chunk staged in LDS (2 KiB);
// inner loop reads LDS float4 broadcasts (wave-uniform -> conflict-free).
// Each (y) writes its own partial buffer with PLAIN stores: no memset, no
// atomics, one fewer dispatch. B sums the NJ partials at load time.
__global__ __launch_bounds__(256) void bsum_kernel(const float* __restrict__ scores,
                                                   float* __restrict__ bsum_part) {
    __shared__ vf4 srow[128];  // 512 floats = 2 KiB
    const int b  = blockIdx.z;
    const int jc = blockIdx.y;
    const int i0 = blockIdx.x * 1024;
    const float* __restrict__ row = scores + b * DIM;

    if (threadIdx.x < 128) srow[threadIdx.x] = ((const vf4*)(row + jc * 512))[threadIdx.x];
    __syncthreads();

    const vf4 xi = ((const vf4*)(row + i0))[threadIdx.x];
    float a0 = 0.f, a1 = 0.f, a2 = 0.f, a3 = 0.f;
    #pragma unroll 4
    for (int jj = 0; jj < 128; ++jj) {
        const vf4 xj = srow[jj];
        a0 += (fabsf(xi.x - xj.x) + fabsf(xi.x - xj.y)) + (fabsf(xi.x - xj.z) + fabsf(xi.x - xj.w));
        a1 += (fabsf(xi.y - xj.x) + fabsf(xi.y - xj.y)) + (fabsf(xi.y - xj.z) + fabsf(xi.y - xj.w));
        a2 += (fabsf(xi.z - xj.x) + fabsf(xi.z - xj.y)) + (fabsf(xi.z - xj.z) + fabsf(xi.z - xj.w));
        a3 += (fabsf(xi.w - xj.x) + fabsf(xi.w - xj.y)) + (fabsf(xi.w - xj.z) + fabsf(xi.w - xj.w));
    }
    vf4 o; o.x = a0; o.y = a1; o.z = a2; o.w = a3;
    vf4* dst = (vf4*)(bsum_part + ((size_t)jc * NB + b) * DIM + i0);
    dst[threadIdx.x] = o;
}

// ---------------- Kernel B: row softmax over i for each (b,k) ----------------
// grid (NK/4, NB), 256 threads = 4 waves; each wave owns ONE k entirely:
// no barriers, no LDS, minimal register liveness. Sums the NJ Bsum partials
// at load time (L2-hit loads, hidden under the 64 MiB write stream).
__global__ __launch_bounds__(256) void softmax_kernel(const float* __restrict__ scores,
                                                      const float* __restrict__ bsum_part,
                                                      float* __restrict__ out) {
    const int b = blockIdx.y;
    const int w = threadIdx.x >> 6;       // wave id within block
    const int t = threadIdx.x & 63;       // lane
    const int k = blockIdx.x * 4 + w;
    const float scale = (float)(DIM - 1 - 2 * k);  // 2047 - 2k

    const vf4* __restrict__ s4 = (const vf4*)(scores + b * DIM);
    const vf4* __restrict__ p0 = (const vf4*)(bsum_part + ((size_t)0 * NB + b) * DIM);
    const vf4* __restrict__ p1 = (const vf4*)(bsum_part + ((size_t)1 * NB + b) * DIM);
    const vf4* __restrict__ p2 = (const vf4*)(bsum_part + ((size_t)2 * NB + b) * DIM);
    const vf4* __restrict__ p3 = (const vf4*)(bsum_part + ((size_t)3 * NB + b) * DIM);

    float e[32];
    #pragma unroll
    for (int q = 0; q < 8; ++q) {
        const int idx = t + 64 * q;
        const vf4 sv = s4[idx];                 // 64 lanes x 16 B contiguous
        const vf4 bv = (p0[idx] + p1[idx]) + (p2[idx] + p3[idx]);
        e[4 * q + 0] = fmaf(sv.x, scale, -bv.x);
        e[4 * q + 1] = fmaf(sv.y, scale, -bv.y);
        e[4 * q + 2] = fmaf(sv.z, scale, -bv.z);
        e[4 * q + 3] = fmaf(sv.w, scale, -bv.w);
    }

    // ---- wave max: 4 local chains then 6-step butterfly ----
    float m0 = e[0], m1 = e[1], m2 = e[2], m3 = e[3];
    #pragma unroll
    for (int j = 4; j < 32; j += 4) {
        m0 = fmaxf(m0, e[j + 0]);
        m1 = fmaxf(m1, e[j + 1]);
        m2 = fmaxf(m2, e[j + 2]);
        m3 = fmaxf(m3, e[j + 3]);
    }
    float m = fmaxf(fmaxf(m0, m1), fmaxf(m2, m3));
    #pragma unroll
    for (int off = 32; off > 0; off >>= 1) m = fmaxf(m, __shfl_xor(m, off, 64));

    // ---- exp + wave sum ----
    float s0 = 0.f, s1 = 0.f, s2 = 0.f, s3 = 0.f;
    #pragma unroll
    for (int j = 0; j < 32; j += 4) {
        e[j + 0] = __expf(e[j + 0] - m); s0 += e[j + 0];
        e[j + 1] = __expf(e[j + 1] - m); s1 += e[j + 1];
        e[j + 2] = __expf(e[j + 2] - m); s2 += e[j + 2];
        e[j + 3] = __expf(e[j + 3] - m); s3 += e[j + 3];
    }
    float s = (s0 + s1) + (s2 + s3);
    #pragma unroll
    for (int off = 32; off > 0; off >>= 1) s += __shfl_xor(s, off, 64);

    const float inv = 1.f / s;
    vf4* o4 = (vf4*)(out + ((size_t)(b * NK + k)) * DIM);
    #pragma unroll
    for (int q = 0; q < 8; ++q) {
        vf4 o;
        o.x = e[4 * q + 0] * inv;
        o.y = e[4 * q + 1] * inv;
        o.z = e[4 * q + 2] * inv;
        o.w = e[4 * q + 3] * inv;
        o4[t + 64 * q] = o;
    }
}

extern "C" void kernel_launch(void* const* d_in, const int* in_sizes, int n_in,
                              void* d_out, int out_size, void* d_ws, size_t ws_size,
                              hipStream_t stream) {
    const float* scores = (const float*)d_in[0];
    float* out = (float*)d_out;
    float* bsum_part = (float*)d_ws;  // NJ * NB * DIM floats = 1 MiB

    bsum_kernel<<<dim3(2, NJ, NB), 256, 0, stream>>>(scores, bsum_part);
    softmax_kernel<<<dim3(NK / 4, NB), 256, 0, stream>>>(scores, bsum_part, out);
}

// Round 7
// 92.381 us; speedup vs baseline: 1.0236x; 1.0236x over previous
//
#include <hip/hip_runtime.h>
#include <math.h>

#define DIM 2048
#define NB 32
#define NK 256

typedef float vf4 __attribute__((ext_vector_type(4)));

// ---------------- Kernel A: Bsum[b,i] = sum_j |s[b,i] - s[b,j]| ----------------
// grid (2, 4, 32): x = i-chunk (1024 i), y = j-chunk (512 j), z = batch.
// 256 threads, 4 consecutive i per thread. j-chunk staged in LDS (2 KiB);
// inner loop reads LDS float4 broadcasts (wave-uniform -> conflict-free).
// Partials merged with atomicAdd after memset. (Round-5 measured-best form:
// single merged bsum keeps kernel B's read set at 16 KB -> L1-resident.)
__global__ __launch_bounds__(256) void bsum_kernel(const float* __restrict__ scores,
                                                   float* __restrict__ bsum) {
    __shared__ vf4 srow[128];  // 512 floats = 2 KiB
    const int b  = blockIdx.z;
    const int j0 = blockIdx.y * 512;
    const int i0 = blockIdx.x * 1024;
    const float* __restrict__ row = scores + b * DIM;

    if (threadIdx.x < 128) srow[threadIdx.x] = ((const vf4*)(row + j0))[threadIdx.x];
    __syncthreads();

    const vf4 xi = ((const vf4*)(row + i0))[threadIdx.x];
    float a0 = 0.f, a1 = 0.f, a2 = 0.f, a3 = 0.f;
    #pragma unroll 4
    for (int jj = 0; jj < 128; ++jj) {
        const vf4 xj = srow[jj];
        a0 += (fabsf(xi.x - xj.x) + fabsf(xi.x - xj.y)) + (fabsf(xi.x - xj.z) + fabsf(xi.x - xj.w));
        a1 += (fabsf(xi.y - xj.x) + fabsf(xi.y - xj.y)) + (fabsf(xi.y - xj.z) + fabsf(xi.y - xj.w));
        a2 += (fabsf(xi.z - xj.x) + fabsf(xi.z - xj.y)) + (fabsf(xi.z - xj.z) + fabsf(xi.z - xj.w));
        a3 += (fabsf(xi.w - xj.x) + fabsf(xi.w - xj.y)) + (fabsf(xi.w - xj.z) + fabsf(xi.w - xj.w));
    }
    float* dst = bsum + b * DIM + i0 + threadIdx.x * 4;
    atomicAdd(dst + 0, a0);
    atomicAdd(dst + 1, a1);
    atomicAdd(dst + 2, a2);
    atomicAdd(dst + 3, a3);
}

// ---------------- Kernel B: row softmax over i for each (b,k) ----------------
// grid (NK/8, NB), 256 threads = 4 waves; each wave owns TWO k sequentially,
// reusing the loaded sv/bv registers across both (one 16 KB load set per wave
// instead of two). No barriers, no LDS. Peak liveness ~ sv+bv+e = ~110 VGPR
// -> 4 waves/SIMD, enough to saturate the 64 MiB write stream.
__global__ __launch_bounds__(256) void softmax_kernel(const float* __restrict__ scores,
                                                      const float* __restrict__ bsum,
                                                      float* __restrict__ out) {
    const int b = blockIdx.y;
    const int w = threadIdx.x >> 6;       // wave id within block
    const int t = threadIdx.x & 63;       // lane
    const int k0 = (blockIdx.x * 4 + w) * 2;

    const vf4* __restrict__ s4  = (const vf4*)(scores + b * DIM);
    const vf4* __restrict__ bs4 = (const vf4*)(bsum   + b * DIM);

    vf4 sv[8], bv[8];
    #pragma unroll
    for (int q = 0; q < 8; ++q) {
        sv[q] = s4[t + 64 * q];    // 64 lanes x 16 B contiguous
        bv[q] = bs4[t + 64 * q];
    }

    #pragma unroll
    for (int kk = 0; kk < 2; ++kk) {
        const int k = k0 + kk;
        const float scale = (float)(DIM - 1 - 2 * k);  // 2047 - 2k

        float e[32];
        #pragma unroll
        for (int q = 0; q < 8; ++q) {
            e[4 * q + 0] = fmaf(sv[q].x, scale, -bv[q].x);
            e[4 * q + 1] = fmaf(sv[q].y, scale, -bv[q].y);
            e[4 * q + 2] = fmaf(sv[q].z, scale, -bv[q].z);
            e[4 * q + 3] = fmaf(sv[q].w, scale, -bv[q].w);
        }

        // ---- wave max: 4 local chains then 6-step butterfly ----
        float m0 = e[0], m1 = e[1], m2 = e[2], m3 = e[3];
        #pragma unroll
        for (int j = 4; j < 32; j += 4) {
            m0 = fmaxf(m0, e[j + 0]);
            m1 = fmaxf(m1, e[j + 1]);
            m2 = fmaxf(m2, e[j + 2]);
            m3 = fmaxf(m3, e[j + 3]);
        }
        float m = fmaxf(fmaxf(m0, m1), fmaxf(m2, m3));
        #pragma unroll
        for (int off = 32; off > 0; off >>= 1) m = fmaxf(m, __shfl_xor(m, off, 64));

        // ---- exp + wave sum ----
        float s0 = 0.f, s1 = 0.f, s2 = 0.f, s3 = 0.f;
        #pragma unroll
        for (int j = 0; j < 32; j += 4) {
            e[j + 0] = __expf(e[j + 0] - m); s0 += e[j + 0];
            e[j + 1] = __expf(e[j + 1] - m); s1 += e[j + 1];
            e[j + 2] = __expf(e[j + 2] - m); s2 += e[j + 2];
            e[j + 3] = __expf(e[j + 3] - m); s3 += e[j + 3];
        }
        float s = (s0 + s1) + (s2 + s3);
        #pragma unroll
        for (int off = 32; off > 0; off >>= 1) s += __shfl_xor(s, off, 64);

        const float inv = 1.f / s;
        vf4* o4 = (vf4*)(out + ((size_t)(b * NK + k)) * DIM);
        #pragma unroll
        for (int q = 0; q < 8; ++q) {
            vf4 o;
            o.x = e[4 * q + 0] * inv;
            o.y = e[4 * q + 1] * inv;
            o.z = e[4 * q + 2] * inv;
            o.w = e[4 * q + 3] * inv;
            o4[t + 64 * q] = o;
        }
    }
}

extern "C" void kernel_launch(void* const* d_in, const int* in_sizes, int n_in,
                              void* d_out, int out_size, void* d_ws, size_t ws_size,
                              hipStream_t stream) {
    const float* scores = (const float*)d_in[0];
    float* out  = (float*)d_out;
    float* bsum = (float*)d_ws;  // NB*DIM floats = 256 KiB

    hipMemsetAsync(bsum, 0, (size_t)NB * DIM * sizeof(float), stream);
    bsum_kernel<<<dim3(2, 4, NB), 256, 0, stream>>>(scores, bsum);
    softmax_kernel<<<dim3(NK / 8, NB), 256, 0, stream>>>(scores, bsum, out);
}